// Round 2
// baseline (526.130 us; speedup 1.0000x reference)
//
#include <hip/hip_runtime.h>
#include <math.h>

#define T_DIM   1024
#define B_DIM   32
#define N_FEAT  1024
#define KW      3
#define NT      32                 // t-chunks for weighted-V pass
#define T_PER   (T_DIM / NT)       // 32
#define EPS     1e-6f

// fast tanh: 1 - 2/(e^{2x}+1); exact at +/-inf, ~1e-6 rel error
__device__ __forceinline__ float tanh_fast(float x) {
  float e = __expf(2.0f * x);
  return 1.0f - 2.0f * __builtin_amdgcn_rcpf(e + 1.0f);
}

// ---------------------------------------------------------------------------
// Kernel 1: fused dual GEMV. wave-per-output, m-major so adjacent waves share
// the W row (L1 reuse). out[b*M+m] = dot(x[b,:], W[m,:]) + bias[m]
// ---------------------------------------------------------------------------
__global__ void __launch_bounds__(256) gemv_kernel(
    const float* __restrict__ q1, const float* __restrict__ sa_w,
    const float* __restrict__ sa_b, const float* __restrict__ q2,
    const float* __restrict__ qk_w, const float* __restrict__ qk_b,
    float* __restrict__ sa_q, float* __restrict__ kern) {
  int gtid = blockIdx.x * 256 + threadIdx.x;
  int wid  = gtid >> 6;
  int lane = threadIdx.x & 63;
  const float *x, *W, *bias;
  float* out;
  int m, b, M;
  if (wid < B_DIM * 1024) {
    M = 1024; m = wid >> 5; b = wid & 31;
    x = q1; W = sa_w; bias = sa_b; out = sa_q;
  } else {
    int w2 = wid - B_DIM * 1024;
    M = 3072; m = w2 >> 5; b = w2 & 31;
    x = q2; W = qk_w; bias = qk_b; out = kern;
  }
  const float4* xr = (const float4*)(x + (size_t)b * N_FEAT);
  const float4* wr = (const float4*)(W + (size_t)m * N_FEAT);
  float acc = 0.f;
#pragma unroll
  for (int j = 0; j < 4; j++) {
    float4 xv = xr[lane + j * 64];
    float4 wv = wr[lane + j * 64];
    acc += xv.x * wv.x + xv.y * wv.y + xv.z * wv.z + xv.w * wv.w;
  }
#pragma unroll
  for (int off = 32; off > 0; off >>= 1) acc += __shfl_down(acc, off, 64);
  if (lane == 0) out[(size_t)b * M + m] = acc + bias[m];
}

// ---------------------------------------------------------------------------
// Kernel 2: one WAVE per (t,b) row. Reads k1,k2 rows (8 KB HBM per wave with
// 8 float4 loads in flight per lane), fast tanh, wave-only reduction.
//   a1t[b][t]     = sum_a tanh(sa_q[b,a] + k1[t,b,a]) * a1_w[a] + a1_b
//   s[b][w][t]    = sum_c k2[t,b,c] * kern[b,c,w]
// ---------------------------------------------------------------------------
__global__ void __launch_bounds__(256) row_dots_kernel(
    const float* __restrict__ k1, const float* __restrict__ k2,
    const float* __restrict__ sa_q, const float* __restrict__ a1_w,
    const float* __restrict__ kern, const float* __restrict__ a1_b,
    float* __restrict__ a1t, float* __restrict__ s_out) {
  int wid  = blockIdx.x * 4 + (threadIdx.x >> 6);   // t*B + b
  int lane = threadIdx.x & 63;
  int b = wid & 31, t = wid >> 5;
  const float4* k1r = (const float4*)(k1 + (size_t)wid * N_FEAT);
  const float4* k2r = (const float4*)(k2 + (size_t)wid * N_FEAT);
  const float4* sqr = (const float4*)(sa_q + (size_t)b * N_FEAT);
  const float4* awr = (const float4*)a1_w;
  const float*  kb  = kern + (size_t)b * (N_FEAT * KW);

  float p1 = 0.f, s0 = 0.f, s1 = 0.f, s2 = 0.f;
#pragma unroll
  for (int j = 0; j < 4; j++) {
    int idx = lane + j * 64;                 // float4 index; features idx*4..+3
    float4 k1v = k1r[idx];
    float4 k2v = k2r[idx];
    float4 sqv = sqr[idx];
    float4 awv = awr[idx];
    const float4* kr = (const float4*)(kb + (size_t)idx * 12);
    float4 ka = kr[0], kc = kr[1], kd = kr[2];
    p1 += tanh_fast(k1v.x + sqv.x) * awv.x
        + tanh_fast(k1v.y + sqv.y) * awv.y
        + tanh_fast(k1v.z + sqv.z) * awv.z
        + tanh_fast(k1v.w + sqv.w) * awv.w;
    // 12 floats = [f0w0 f0w1 f0w2 f1w0 f1w1 f1w2 f2w0 f2w1 f2w2 f3w0 f3w1 f3w2]
    s0 += k2v.x * ka.x + k2v.y * ka.w + k2v.z * kc.z + k2v.w * kd.y;
    s1 += k2v.x * ka.y + k2v.y * kc.x + k2v.z * kc.w + k2v.w * kd.z;
    s2 += k2v.x * ka.z + k2v.y * kc.y + k2v.z * kd.x + k2v.w * kd.w;
  }
  float vals[4] = {p1, s0, s1, s2};
#pragma unroll
  for (int off = 32; off > 0; off >>= 1) {
#pragma unroll
    for (int j = 0; j < 4; j++) vals[j] += __shfl_down(vals[j], off, 64);
  }
  if (lane == 0) {
    a1t[(size_t)b * T_DIM + t] = vals[0] + a1_b[0];
    float* sb = s_out + (size_t)b * (3 * T_DIM);
    sb[t]              = vals[1];
    sb[T_DIM + t]      = vals[2];
    sb[2 * T_DIM + t]  = vals[3];
  }
}

// ---------------------------------------------------------------------------
// block reduce over 1024 threads (16 waves), result broadcast
// ---------------------------------------------------------------------------
__device__ __forceinline__ float block_reduce_1024(float v, bool is_max,
                                                   float* sm /*[16]*/) {
#pragma unroll
  for (int off = 32; off > 0; off >>= 1) {
    float o = __shfl_down(v, off, 64);
    v = is_max ? fmaxf(v, o) : v + o;
  }
  int wave = threadIdx.x >> 6;
  if ((threadIdx.x & 63) == 0) sm[wave] = v;
  __syncthreads();
  float r = sm[0];
#pragma unroll
  for (int i = 1; i < 16; i++) r = is_max ? fmaxf(r, sm[i]) : r + sm[i];
  __syncthreads();
  return r;
}

// ---------------------------------------------------------------------------
// Kernel 3: masked softmax over T for both paths. One block (1024 thr) per b.
//   a2[t] = s[b][0][t-1] + s[b][1][t] + s[b][2][t+1]   (zero at edges)
// ---------------------------------------------------------------------------
__global__ void __launch_bounds__(1024) softmax_kernel(
    const float* __restrict__ a1t, const float* __restrict__ s,
    const float* __restrict__ k_mask,
    float* __restrict__ e1t, float* __restrict__ e2t) {
  int b = blockIdx.x, t = threadIdx.x;
  __shared__ float sm[16];
  float x1 = a1t[(size_t)b * T_DIM + t];
  const float* sb = s + (size_t)b * (3 * T_DIM);
  float sl = (t > 0)         ? sb[t - 1]            : 0.f;
  float sc =                   sb[T_DIM + t];
  float sr = (t < T_DIM - 1) ? sb[2 * T_DIM + t + 1] : 0.f;
  float x2 = sl + sc + sr;
  float mk = k_mask[(size_t)t * B_DIM + b];

  float m1 = block_reduce_1024(x1, true, sm);
  float m2 = block_reduce_1024(x2, true, sm);
  float v1 = __expf(x1 - m1) * mk;
  float v2 = __expf(x2 - m2) * mk;
  float sum1 = block_reduce_1024(v1, false, sm);
  float sum2 = block_reduce_1024(v2, false, sm);
  e1t[(size_t)b * T_DIM + t] = v1 / sum1;
  e2t[(size_t)b * T_DIM + t] = v2 / sum2;
}

// ---------------------------------------------------------------------------
// Kernel 4: weighted sum over V, both paths fused into ONE partial.
// grid = (B, NT) = 1024 blocks (4/CU); 256 thr x float4 = 1024 feats.
// ---------------------------------------------------------------------------
__global__ void __launch_bounds__(256) weighted_v_kernel(
    const float* __restrict__ v1, const float* __restrict__ v2,
    const float* __restrict__ e1t, const float* __restrict__ e2t,
    float* __restrict__ partial) {
  int b  = blockIdx.x;
  int tc = blockIdx.y;
  int tid = threadIdx.x;
  __shared__ float se1[T_PER], se2[T_PER];
  if (tid < T_PER)
    se1[tid] = e1t[(size_t)b * T_DIM + tc * T_PER + tid];
  else if (tid < 2 * T_PER)
    se2[tid - T_PER] = e2t[(size_t)b * T_DIM + tc * T_PER + (tid - T_PER)];
  __syncthreads();

  float4 acc = {0.f, 0.f, 0.f, 0.f};
  size_t dofs = (size_t)tid * 4;
#pragma unroll 8
  for (int i = 0; i < T_PER; i++) {
    size_t row = ((size_t)(tc * T_PER + i) * B_DIM + b) * N_FEAT + dofs;
    float4 a = *(const float4*)(v1 + row);
    float4 c = *(const float4*)(v2 + row);
    float w1 = se1[i], w2 = se2[i];
    acc.x += w1 * a.x + w2 * c.x;
    acc.y += w1 * a.y + w2 * c.y;
    acc.z += w1 * a.z + w2 * c.z;
    acc.w += w1 * a.w + w2 * c.w;
  }
  *(float4*)(partial + ((size_t)tc * B_DIM + b) * N_FEAT + dofs) = acc;
}

// ---------------------------------------------------------------------------
// Kernel 5: reduce partials over NT chunks + LayerNorm. One block per b.
// ---------------------------------------------------------------------------
__global__ void __launch_bounds__(1024) ln_kernel(
    const float* __restrict__ partial, const float* __restrict__ ln_g,
    const float* __restrict__ ln_b, float* __restrict__ out) {
  int b = blockIdx.x;
  int d = threadIdx.x;
  __shared__ float sm[16];
  float x = 0.f;
#pragma unroll
  for (int j = 0; j < NT; j++)
    x += partial[((size_t)j * B_DIM + b) * N_FEAT + d];
  float ssum = block_reduce_1024(x, false, sm);
  float mu = ssum * (1.f / N_FEAT);
  float dx = x - mu;
  float vsum = block_reduce_1024(dx * dx, false, sm);
  float inv = rsqrtf(vsum * (1.f / N_FEAT) + EPS);
  out[(size_t)b * N_FEAT + d] = dx * inv * ln_g[d] + ln_b[d];
}

// ---------------------------------------------------------------------------
extern "C" void kernel_launch(void* const* d_in, const int* in_sizes, int n_in,
                              void* d_out, int out_size, void* d_ws, size_t ws_size,
                              hipStream_t stream) {
  const float* q1     = (const float*)d_in[0];
  const float* k1     = (const float*)d_in[1];
  const float* v1     = (const float*)d_in[2];
  const float* q2     = (const float*)d_in[3];
  const float* k2     = (const float*)d_in[4];
  const float* v2     = (const float*)d_in[5];
  const float* k_mask = (const float*)d_in[6];
  const float* sa_w   = (const float*)d_in[7];
  const float* sa_b   = (const float*)d_in[8];
  const float* a1_w   = (const float*)d_in[9];
  const float* a1_b   = (const float*)d_in[10];
  const float* qk_w   = (const float*)d_in[11];
  const float* qk_b   = (const float*)d_in[12];
  const float* ln_g   = (const float*)d_in[13];
  const float* ln_bp  = (const float*)d_in[14];
  float* out = (float*)d_out;
  float* ws  = (float*)d_ws;

  // ws layout (floats)
  float* sa_q    = ws;                       // 32768        [b][m]
  float* kern    = sa_q + 32768;             // 98304        [b][c][w]
  float* s       = kern + 98304;             // 98304        [b][w][t]
  float* a1t     = s + 98304;                // 32768        [b][t]
  float* e1t     = a1t + 32768;              // 32768        [b][t]
  float* e2t     = e1t + 32768;              // 32768        [b][t]
  float* partial = e2t + 32768;              // NT*B*N = 1048576 (4 MiB)

  // 1) both GEMVs fused: 32768 + 98304 waves = 32768 blocks
  gemv_kernel<<<dim3(32768), 256, 0, stream>>>(
      q1, sa_w, sa_b, q2, qk_w, qk_b, sa_q, kern);
  // 2) a1 + conv taps (reads k1,k2: 256 MiB), wave per row
  row_dots_kernel<<<dim3(T_DIM * B_DIM / 4), 256, 0, stream>>>(
      k1, k2, sa_q, a1_w, kern, a1_b, a1t, s);
  // 3) softmax both paths
  softmax_kernel<<<dim3(B_DIM), 1024, 0, stream>>>(a1t, s, k_mask, e1t, e2t);
  // 4) weighted V sums, fused paths (reads v1,v2: 256 MiB)
  weighted_v_kernel<<<dim3(B_DIM, NT), 256, 0, stream>>>(v1, v2, e1t, e2t, partial);
  // 5) combine + LayerNorm
  ln_kernel<<<dim3(B_DIM), 1024, 0, stream>>>(partial, ln_g, ln_bp, out);
}